// Round 12
// baseline (19.101 us; speedup 1.0000x reference)
//
#include <hip/hip_runtime.h>
#include <hip/hip_bf16.h>

typedef _Float16 f16;
typedef f16 f16x2 __attribute__((ext_vector_type(2)));
typedef f16 f16x4 __attribute__((ext_vector_type(4)));
typedef f16 f16x8 __attribute__((ext_vector_type(8)));
typedef float f32x4 __attribute__((ext_vector_type(4)));
typedef float f32x16 __attribute__((ext_vector_type(16)));

constexpr int B_  = 4;
constexpr int H_  = 128;
constexpr int W_  = 128;
constexpr int C_  = 64;
constexpr int NH_ = 4;
constexpr int D_  = 16;
constexpr int KK_ = 25;

constexpr int TW_  = 8, TH_ = 8;
constexpr int HWID = 12, HHEI = 12;
constexpr int NPX  = HHEI * HWID;          // 144 halo pixels
// LDS layout (R8/R11 proven):
//   [0    , 18432) abuf  [144][64] f16, chunk-XOR swizzled; staged ref -> r in-place
//   [18432, 26624) mabuf [64][64]  f16; staged main -> q in-place
//   [0    , 27648) xbuf  f32 prob exchange (aliases the above, fenced)
//   [27648, 31744) msbuf [2][4][64] float2 (m,s)
constexpr int MOFF  = NPX * 64 * 2;        // 18432
constexpr int MSOFF = 27648;
constexpr int SMEM  = 31744;               // <= 40960 -> 4 blocks/CU (wave cap)
constexpr int PSTRIDE = KK_ + 2;           // 27
constexpr int PSLAB   = 64 * PSTRIDE;      // 1728 f32

#if __has_builtin(__builtin_amdgcn_fdot2)
#define FDOT2(a, b, c) __builtin_amdgcn_fdot2((a), (b), (c), false)
#else
#define FDOT2(a, b, c) fmaf((float)(a)[1], (float)(b)[1], fmaf((float)(a)[0], (float)(b)[0], (c)))
#endif

__device__ __forceinline__ int div12(int x) { return (x * 171) >> 11; }  // exact for 0..143

__global__ __launch_bounds__(512, 8) void rl8mh12(
    const float* __restrict__ mainp, const float* __restrict__ refp,
    const float* __restrict__ wmain, const float* __restrict__ wref,
    float* __restrict__ out)
{
    __shared__ __align__(16) unsigned char smraw[SMEM];
    f16*    abuf  = (f16*)smraw;             // staged ref halo -> rbuf in-place
    f16*    mabuf = (f16*)(smraw + MOFF);    // staged main     -> qbuf in-place
    float*  xbuf  = (float*)smraw;
    float2* msbuf = (float2*)(smraw + MSOFF);

    const int tid = threadIdx.x;
    const int l   = tid & 63;
    const int wid = __builtin_amdgcn_readfirstlane(tid >> 6);  // 0..7
    const int n   = wid & 3;    // head   (logit phase)
    const int h   = wid >> 2;   // half   (logit phase)
    const int p   = wid & 1;    // head-pair (proj phase): heads 2p, 2p+1
    const int g   = wid >> 1;   // tile group (proj phase)

    // XCD-chunked swizzle (bijective, 256 % 8 == 0)
    const int bid = blockIdx.y * 16 + blockIdx.x;
    const int swz = (bid & 7) * 32 + (bid >> 3);
    const int x0 = (swz & 15) * TW_;
    const int y0 = (swz >> 4) * TH_;
    const int b  = blockIdx.z;
    const float* mainb = mainp + ((size_t)b * H_) * W_ * C_;
    const float* refb  = refp  + ((size_t)b * H_) * W_ * C_;

    // ---- Phase 0: staging, f32 -> f16, 8-f16-chunk XOR swizzle, b128 writes ----
    // halo: 1152 units (144 px x 8 chunks), each = 2 float4 loads -> 1 f16x8 write
    auto stage_halo = [&](int j) {
        int px = j >> 3, pc = j & 7;
        int hy = div12(px), hx = px - hy * HWID;
        int gy = y0 + hy - 2, gx = x0 + hx - 2;
        float4 va = make_float4(0.f,0.f,0.f,0.f), vb = va;
        if ((unsigned)gy < (unsigned)H_ && (unsigned)gx < (unsigned)W_) {
            const float4* src = (const float4*)(refb + ((size_t)gy * W_ + gx) * C_);
            va = src[pc * 2]; vb = src[pc * 2 + 1];
        }
        f16x8 h8 = {(f16)va.x,(f16)va.y,(f16)va.z,(f16)va.w,
                    (f16)vb.x,(f16)vb.y,(f16)vb.z,(f16)vb.w};
        *(f16x8*)(abuf + px * 64 + ((pc ^ (px & 7)) << 3)) = h8;
    };
    stage_halo(tid);
    stage_halo(tid + 512);
    if (tid < 128) stage_halo(tid + 1024);
    {   // main: 512 units (64 px x 8 chunks)
        int px = tid >> 3, pc = tid & 7;
        int gy = y0 + (px >> 3), gx = x0 + (px & 7);
        const float4* src = (const float4*)(mainb + ((size_t)gy * W_ + gx) * C_);
        float4 va = src[pc * 2], vb = src[pc * 2 + 1];
        f16x8 h8 = {(f16)va.x,(f16)va.y,(f16)va.z,(f16)va.w,
                    (f16)vb.x,(f16)vb.y,(f16)vb.z,(f16)vb.w};
        *(f16x8*)(mabuf + px * 64 + ((pc ^ (px & 7)) << 3)) = h8;
    }
    __syncthreads();   // bar1

    // ---- Phase 1: projections, 32x32x16 MFMA, 2 heads stacked in A ----
    // A row = lane&31 -> head = p*2 + (row>>4), d = row&15; k = (lane>>5)*8 + i.
    // B col = lane&31 -> pixel; same k mapping. 4 K-steps of 16 cover C=64.
    f16x8 A[4];
    {
        const float* wsrc = (g == 3) ? wmain : wref;
        int rowA = l & 31;
        const float* w = wsrc + (p * 2 + (rowA >> 4)) * C_ * D_ + (rowA & 15);
        int kbase = (l >> 5) * 8;
        #pragma unroll
        for (int s = 0; s < 4; ++s) {
            union { f16x8 v; f16 e[8]; } u;
            #pragma unroll
            for (int i = 0; i < 8; ++i)
                u.e[i] = (f16)w[(s * 16 + kbase + i) * D_];
            A[s] = u.v;
        }
    }

    auto proj32 = [&](const f16* src, int pbase, f16x4* o) {
        int px = pbase + (l & 31);
        const f16* rp = src + px * 64;
        f32x16 acc = {};
        #pragma unroll
        for (int s = 0; s < 4; ++s) {
            f16x8 Bv = *(const f16x8*)(rp + (((s * 2 + (l >> 5)) ^ (px & 7)) << 3));
            acc = __builtin_amdgcn_mfma_f32_32x32x16_f16(A[s], Bv, acc, 0, 0, 0);
        }
        #pragma unroll
        for (int cc = 0; cc < 4; ++cc)
            o[cc] = f16x4{(f16)acc[4*cc], (f16)acc[4*cc+1],
                          (f16)acc[4*cc+2], (f16)acc[4*cc+3]};
    };
    // reg chunk cc -> head p*2+(cc>>1), d0 = (cc&1)*8 + 4*(lane>>5)
    auto wrout32 = [&](f16* dst, int pbase, int nvalid, const f16x4* o) {
        int px = pbase + (l & 31);
        if ((l & 31) < nvalid) {
            int hi = l >> 5;
            #pragma unroll
            for (int cc = 0; cc < 4; ++cc) {
                int c = (p * 2 + (cc >> 1)) * 2 + (cc & 1);   // 8-f16 chunk index
                *(f16x4*)(dst + px * 64 + (((c ^ (px & 7)) << 3) | (hi << 2))) = o[cc];
            }
        }
    };

    f16x4 oA[4], oB[4];
    if      (g == 0) { proj32(abuf,   0, oA); proj32(abuf,  32, oB); }
    else if (g == 1) { proj32(abuf,  64, oA); proj32(abuf,  96, oB); }
    else if (g == 2) { proj32(abuf, 128, oA); }   // px 144..159 lanes read garbage, discarded
    else             { proj32(mabuf,  0, oA); proj32(mabuf, 32, oB); }
    __syncthreads();   // bar2: all staged reads done -> safe to overwrite

    if      (g == 0) { wrout32(abuf,   0, 32, oA); wrout32(abuf,  32, 32, oB); }
    else if (g == 1) { wrout32(abuf,  64, 32, oA); wrout32(abuf,  96, 32, oB); }
    else if (g == 2) { wrout32(abuf, 128, 16, oA); }
    else             { wrout32(mabuf,  0, 32, oA); wrout32(mabuf, 32, 32, oB); }
    __syncthreads();   // bar3: rbuf/qbuf ready

    // ---- per-thread q fragment (pixel = lane) — unchanged from R11 ----
    const int py  = l >> 3;
    const int pxx = l & 7;
    f16x8 q0 = *(const f16x8*)(mabuf + l * 64 + ((((n << 1) | 0) ^ (l & 7)) << 3));
    f16x8 q1 = *(const f16x8*)(mabuf + l * 64 + ((((n << 1) | 1) ^ (l & 7)) << 3));
    const f16x2* q2a = (const f16x2*)&q0;
    const f16x2* q2b = (const f16x2*)&q1;

    // ---- logits: half h computes 13 (or 12) offsets — unchanged ----
    float lg[13];
    auto do_lg = [&](int idx, int k) {
        int ky = k / 5, kx = k % 5;              // compile-time
        int np = (py + ky) * 12 + pxx + kx;
        const f16* rp = abuf + np * 64;
        f16x8 r0 = *(const f16x8*)(rp + ((((n << 1) | 0) ^ (np & 7)) << 3));
        f16x8 r1 = *(const f16x8*)(rp + ((((n << 1) | 1) ^ (np & 7)) << 3));
        const f16x2* r2a = (const f16x2*)&r0;
        const f16x2* r2b = (const f16x2*)&r1;
        float a = 0.f;
        #pragma unroll
        for (int j = 0; j < 4; ++j) a = FDOT2(q2a[j], r2a[j], a);
        #pragma unroll
        for (int j = 0; j < 4; ++j) a = FDOT2(q2b[j], r2b[j], a);
        lg[idx] = a;
    };
    if (h == 0) {
        do_lg(0,0);  do_lg(1,1);  do_lg(2,2);  do_lg(3,3);  do_lg(4,4);
        do_lg(5,5);  do_lg(6,6);  do_lg(7,7);  do_lg(8,8);  do_lg(9,9);
        do_lg(10,10); do_lg(11,11); do_lg(12,12);
    } else {
        do_lg(0,13); do_lg(1,14); do_lg(2,15); do_lg(3,16); do_lg(4,17);
        do_lg(5,18); do_lg(6,19); do_lg(7,20); do_lg(8,21); do_lg(9,22);
        do_lg(10,23); do_lg(11,24);
        lg[12] = -1e30f;   // dead slot -> exp()=0
    }

    // ---- online split softmax: single (m,s) exchange — unchanged ----
    float mloc = lg[0];
    #pragma unroll
    for (int k = 1; k < 13; ++k) mloc = fmaxf(mloc, lg[k]);

    float s = 0.f;
    f16x2 pk[7];
    #pragma unroll
    for (int j = 0; j < 6; ++j) {
        float e0 = __expf(lg[2*j]   - mloc);
        float e1 = __expf(lg[2*j+1] - mloc);
        s += e0 + e1;
        pk[j] = f16x2{(f16)e0, (f16)e1};
    }
    {
        float e12 = __expf(lg[12] - mloc);
        s += e12;
        pk[6] = f16x2{(f16)e12, (f16)0.f};
    }
    msbuf[(h * 4 + n) * 64 + l] = make_float2(mloc, s);
    __syncthreads();   // bar4
    float2 o = msbuf[((1 - h) * 4 + n) * 64 + l];
    float m    = fmaxf(mloc, o.x);
    float sc   = __expf(mloc - m);
    float osc  = __expf(o.x  - m);
    float inv  = sc / (s * sc + o.y * osc);

    // ---- write probs (xbuf aliases abuf/mabuf; fenced by bar4) — unchanged ----
    {
        float* dst = &xbuf[n * PSLAB + l * PSTRIDE + h * 13];
        #pragma unroll
        for (int j = 0; j < 6; ++j) {
            dst[2*j]     = (float)pk[j][0] * inv;
            dst[2*j + 1] = (float)pk[j][1] * inv;
        }
        if (h == 0) dst[12] = (float)pk[6][0] * inv;
    }
    __syncthreads();   // bar5

    // ---- head-average + store — unchanged ----
    for (int i = tid; i < TW_ * TH_ * KK_; i += 512) {
        int p2 = i / KK_;
        int k  = i - p2 * KK_;
        int off = p2 * PSTRIDE + k;
        float v = 0.25f * (xbuf[off] + xbuf[PSLAB + off] + xbuf[2 * PSLAB + off] + xbuf[3 * PSLAB + off]);
        out[(((size_t)b * H_ + (y0 + (p2 >> 3))) * W_ + (x0 + (p2 & 7))) * KK_ + k] = v;
    }
}

extern "C" void kernel_launch(void* const* d_in, const int* in_sizes, int n_in,
                              void* d_out, int out_size, void* d_ws, size_t ws_size,
                              hipStream_t stream) {
    const float* mainp = (const float*)d_in[0];
    const float* refp  = (const float*)d_in[1];
    const float* wmain = (const float*)d_in[2];
    const float* wref  = (const float*)d_in[3];
    float* outp = (float*)d_out;

    dim3 grid(W_ / TW_, H_ / TH_, B_);
    rl8mh12<<<grid, dim3(512), 0, stream>>>(mainp, refp, wmain, wref, outp);
}